// Round 3
// baseline (408.590 us; speedup 1.0000x reference)
//
#include <hip/hip_runtime.h>

typedef __attribute__((ext_vector_type(8))) short short8;
typedef __attribute__((ext_vector_type(4))) float f32x4;
typedef unsigned short u16;
typedef unsigned int u32;

__device__ __forceinline__ u16 f2bf(float f) {
  union { float f; unsigned int u; } v; v.f = f;
  unsigned int r = (v.u + 0x7FFFu + ((v.u >> 16) & 1u)) >> 16;
  return (u16)r;
}
__device__ __forceinline__ float bf2f(u16 b) {
  union { unsigned int u; float f; } v; v.u = ((unsigned int)b) << 16;
  return v.f;
}
__device__ __forceinline__ void load_lds16(const void* g, void* l) {
  __builtin_amdgcn_global_load_lds((const __attribute__((address_space(1))) void*)g,
                                   (__attribute__((address_space(3))) void*)l, 16, 0, 0);
}

// ---------------- fp32 -> bf16 elementwise ----------------
__global__ void cvt_f32_bf16_kernel(const float* __restrict__ in, u16* __restrict__ out, int n4) {
  int i = blockIdx.x * blockDim.x + threadIdx.x;
  if (i >= n4) return;
  float4 v = ((const float4*)in)[i];
  ushort4 o;
  o.x = f2bf(v.x); o.y = f2bf(v.y); o.z = f2bf(v.z); o.w = f2bf(v.w);
  ((ushort4*)out)[i] = o;
}

// ---------------- fp32 [K][N] -> bf16 [N][K] transpose ----------------
__global__ void tconv_f32_kernel(const float* __restrict__ W, u16* __restrict__ Wt, int K, int N) {
  __shared__ float tile[32][33];
  int tx = threadIdx.x, ty = threadIdx.y;
  int nb = blockIdx.x * 32, kb = blockIdx.y * 32;
#pragma unroll
  for (int i = ty; i < 32; i += 8)
    tile[i][tx] = W[(size_t)(kb + i) * N + nb + tx];
  __syncthreads();
#pragma unroll
  for (int i = ty; i < 32; i += 8)
    Wt[(size_t)(nb + i) * K + kb + tx] = f2bf(tile[tx][i]);
}

// ---------------- bf16 [R][C-slice] -> bf16 [C][R] transpose ----------------
__global__ void t_bf16_kernel(const u16* __restrict__ V, u16* __restrict__ Vt, int ldv, int R, int C) {
  __shared__ u16 tile[32][33];
  int tx = threadIdx.x, ty = threadIdx.y;
  int cb = blockIdx.x * 32, rb = blockIdx.y * 32;
#pragma unroll
  for (int i = ty; i < 32; i += 8)
    tile[i][tx] = V[(size_t)(rb + i) * ldv + cb + tx];
  __syncthreads();
#pragma unroll
  for (int i = ty; i < 32; i += 8)
    Vt[(size_t)(cb + i) * R + rb + tx] = tile[tx][i];
}

// ---------------- RoPE in-place on bf16 [S][*], head cols at hh*128 ----------------
__global__ void rope_kernel(u16* __restrict__ X, int ld, int hmask, int hshift, int total, float scale) {
  int idx = blockIdx.x * blockDim.x + threadIdx.x;
  if (idx >= total) return;
  int j = idx & 63;
  int t = idx >> 6;
  int hh = t & hmask;
  int s = t >> hshift;
  float invf = exp2f(-(float)j * (13.287712379549449f / 64.0f)); // 10000^(-j/64)
  float ang = (float)s * invf;
  float sn, cs;
  sincosf(ang, &sn, &cs);
  u16* p = X + (size_t)s * ld + hh * 128 + j;
  float a = bf2f(p[0]), b = bf2f(p[64]);
  p[0]  = f2bf((a * cs - b * sn) * scale);
  p[64] = f2bf((b * cs + a * sn) * scale);
}

// ---------------- bf16 GEMM: C[M][N] = A[M][K] * Bt[N][K]^T ----------------
template<int OUTF32>
__global__ __launch_bounds__(256, 2) void gemm_bt_kernel(
    const u16* __restrict__ A, const u16* __restrict__ B,
    void* __restrict__ C, int M, int N, int K) {
  __shared__ u16 As[128 * 64];
  __shared__ u16 Bs[128 * 64];
  int tid = threadIdx.x, lane = tid & 63, w = tid >> 6;
  int wr = w >> 1, wc = w & 1;
  int nbx = gridDim.x;
  int flat = blockIdx.y * nbx + blockIdx.x;
  int cpx = (nbx * gridDim.y) >> 3;
  flat = (flat & 7) * cpx + (flat >> 3);
  int m0 = (flat / nbx) * 128, n0 = (flat % nbx) * 128;
  f32x4 acc[4][4];
#pragma unroll
  for (int i = 0; i < 4; ++i)
#pragma unroll
    for (int j = 0; j < 4; ++j) acc[i][j] = (f32x4){0.f, 0.f, 0.f, 0.f};
  int srow = tid >> 3;
  int scol = ((tid & 7) ^ (srow & 7)) << 3;
  const u16* ga = A + (size_t)(m0 + srow) * K + scol;
  const u16* gb = B + (size_t)(n0 + srow) * K + scol;
  int xorm = (lane & 7) << 3;
  int arow = wr * 64 + (lane & 15);
  int brow = wc * 64 + (lane & 15);
  int c0 = (lane >> 4) << 3;
  int nkt = K >> 6;
  for (int kt = 0; kt < nkt; ++kt) {
#pragma unroll
    for (int it = 0; it < 4; ++it) {
      load_lds16(ga + (size_t)it * 32 * K + kt * 64, (char*)As + (it * 256 + w * 64) * 16);
      load_lds16(gb + (size_t)it * 32 * K + kt * 64, (char*)Bs + (it * 256 + w * 64) * 16);
    }
    __syncthreads();
#pragma unroll
    for (int kk = 0; kk < 2; ++kk) {
      int col = (kk * 32 + c0) ^ xorm;
      short8 af[4], bfr[4];
#pragma unroll
      for (int m = 0; m < 4; ++m) af[m]  = *(const short8*)&As[(arow + m * 16) * 64 + col];
#pragma unroll
      for (int n = 0; n < 4; ++n) bfr[n] = *(const short8*)&Bs[(brow + n * 16) * 64 + col];
#pragma unroll
      for (int m = 0; m < 4; ++m)
#pragma unroll
        for (int n = 0; n < 4; ++n)
          acc[m][n] = __builtin_amdgcn_mfma_f32_16x16x32_bf16(af[m], bfr[n], acc[m][n], 0, 0, 0);
    }
    __syncthreads();
  }
  int crow = m0 + wr * 64 + ((lane >> 4) << 2);
  int ccol = n0 + wc * 64 + (lane & 15);
#pragma unroll
  for (int m = 0; m < 4; ++m)
#pragma unroll
    for (int n = 0; n < 4; ++n)
#pragma unroll
      for (int r = 0; r < 4; ++r) {
        size_t off = (size_t)(crow + m * 16 + r) * N + ccol + n * 16;
        if (OUTF32) ((float*)C)[off] = acc[m][n][r];
        else        ((u16*)C)[off]   = f2bf(acc[m][n][r]);
      }
}

// ---------------- flash attention, sliding window 1024, GQA 32/8 ----------------
// grid (S/64, H). block 256 = 4 waves; wave w owns q rows [q0+16w, +16).
// K,V double-buffered; ONE barrier + vmcnt(0) per KV tile.
// Q pre-scaled by log2(e)/sqrt(D) -> exp2-domain softmax.
__global__ __launch_bounds__(256, 2) void attn_kernel(
    const u16* __restrict__ Q, const u16* __restrict__ Kg,
    const u16* __restrict__ Vt, u16* __restrict__ O) {
  __shared__ u16 Ks[2][64 * 128];
  __shared__ u16 Vs[2][128 * 64];
  __shared__ u16 Ps[4][16 * 72];
  int tid = threadIdx.x, lane = tid & 63, w = tid >> 6;
  int q0 = blockIdx.x * 64;
  int h = blockIdx.y, hk = h >> 2;
  int qrow = q0 + w * 16;
  short8 qf[4];
  {
    const u16* qp = Q + (size_t)(qrow + (lane & 15)) * 4096 + h * 128 + ((lane >> 4) << 3);
#pragma unroll
    for (int kk = 0; kk < 4; ++kk) qf[kk] = *(const short8*)(qp + kk * 32);
  }
  float m[4], lsum[4];
  f32x4 of[8];
#pragma unroll
  for (int r = 0; r < 4; ++r) { m[r] = -1e30f; lsum[r] = 0.f; }
#pragma unroll
  for (int d = 0; d < 8; ++d) of[d] = (f32x4){0.f, 0.f, 0.f, 0.f};
  int jt_lo = (q0 >= 1024) ? ((q0 - 1023) >> 6) : 0;
  int jt_hi = q0 >> 6;
  int xorm = (lane & 7) << 3;
  int c0 = (lane >> 4) << 3;
  int krow = tid >> 4;
  int kchunk = (tid & 15) ^ (krow & 7);
  const u16* kbase = Kg + (size_t)krow * 2048 + hk * 128 + (kchunk << 3);
  int vrow = tid >> 3;
  int vchunk = (tid & 7) ^ (vrow & 7);
  const u16* vbase = Vt + (size_t)(hk * 128 + vrow) * 2048 + (vchunk << 3);

  auto stageK = [&](int buf, int j0) {
    const u16* g = kbase + (size_t)j0 * 2048;
#pragma unroll
    for (int it = 0; it < 4; ++it)
      load_lds16(g + (size_t)it * 16 * 2048, (char*)(&Ks[buf][0]) + (it * 256 + w * 64) * 16);
  };
  auto stageV = [&](int buf, int j0) {
    const u16* g = vbase + j0;
#pragma unroll
    for (int it = 0; it < 4; ++it)
      load_lds16(g + (size_t)it * 32 * 2048, (char*)(&Vs[buf][0]) + (it * 256 + w * 64) * 16);
  };

  int cur = 0;
  stageK(0, jt_lo << 6);
  stageV(0, jt_lo << 6);
  asm volatile("s_waitcnt vmcnt(0)" ::: "memory");
  __syncthreads();
  for (int jt = jt_lo; jt <= jt_hi; ++jt) {
    int j0 = jt << 6;
    if (jt < jt_hi) { stageK(cur ^ 1, j0 + 64); stageV(cur ^ 1, j0 + 64); } // 8 loads in flight
    // scores = Q K^T (log2-domain)
    f32x4 sf[4];
#pragma unroll
    for (int nt = 0; nt < 4; ++nt) sf[nt] = (f32x4){0.f, 0.f, 0.f, 0.f};
    const u16* ks = &Ks[cur][0];
    __builtin_amdgcn_s_setprio(1);
#pragma unroll
    for (int kk = 0; kk < 4; ++kk) {
      short8 a = qf[kk];
      int col = (kk * 32 + c0) ^ xorm;
#pragma unroll
      for (int nt = 0; nt < 4; ++nt) {
        short8 b = *(const short8*)&ks[(nt * 16 + (lane & 15)) * 128 + col];
        sf[nt] = __builtin_amdgcn_mfma_f32_16x16x32_bf16(a, b, sf[nt], 0, 0, 0);
      }
    }
    __builtin_amdgcn_s_setprio(0);
    // mask (boundary tiles only) + online softmax (exp2 domain, defer-max)
    float pv[4][4];
#pragma unroll
    for (int nt = 0; nt < 4; ++nt)
#pragma unroll
      for (int r = 0; r < 4; ++r) pv[nt][r] = sf[nt][r];
    if (j0 + 63 > qrow || j0 + 1024 <= qrow + 15) {
      int kb = j0 + (lane & 15);
      int qb = qrow + ((lane >> 4) << 2);
#pragma unroll
      for (int nt = 0; nt < 4; ++nt)
#pragma unroll
        for (int r = 0; r < 4; ++r) {
          int key = kb + nt * 16, qq = qb + r;
          if (key > qq || key + 1024 <= qq) pv[nt][r] = -1e9f;
        }
    }
#pragma unroll
    for (int r = 0; r < 4; ++r) {
      float tm = fmaxf(fmaxf(pv[0][r], pv[1][r]), fmaxf(pv[2][r], pv[3][r]));
      tm = fmaxf(tm, __shfl_xor(tm, 1));
      tm = fmaxf(tm, __shfl_xor(tm, 2));
      tm = fmaxf(tm, __shfl_xor(tm, 4));
      tm = fmaxf(tm, __shfl_xor(tm, 8));
      if (__any(tm > m[r] + 8.f)) {           // defer-max: rescale only when needed
        float nm = fmaxf(m[r], tm);
        float sc = __builtin_amdgcn_exp2f(m[r] - nm);
        m[r] = nm;
        lsum[r] *= sc;
#pragma unroll
        for (int d = 0; d < 8; ++d) of[d][r] *= sc;
      }
      float ps = 0.f;
#pragma unroll
      for (int nt = 0; nt < 4; ++nt) {
        float p = __builtin_amdgcn_exp2f(pv[nt][r] - m[r]);
        pv[nt][r] = p;
        ps += p;
      }
      ps += __shfl_xor(ps, 1);
      ps += __shfl_xor(ps, 2);
      ps += __shfl_xor(ps, 4);
      ps += __shfl_xor(ps, 8);
      lsum[r] += ps;
    }
    // P -> wave-private LDS (bf16, truncating convert), pitch 72
#pragma unroll
    for (int nt = 0; nt < 4; ++nt)
#pragma unroll
      for (int r = 0; r < 4; ++r)
        Ps[w][(((lane >> 4) << 2) + r) * 72 + nt * 16 + (lane & 15)] =
            (u16)(__float_as_uint(pv[nt][r]) >> 16);
    asm volatile("s_waitcnt lgkmcnt(0)" ::: "memory");
    __builtin_amdgcn_sched_barrier(0);
    // O += P V
    const u16* vs = &Vs[cur][0];
    __builtin_amdgcn_s_setprio(1);
#pragma unroll
    for (int kh = 0; kh < 2; ++kh) {
      short8 a = *(const short8*)&Ps[w][(lane & 15) * 72 + kh * 32 + c0];
      int col = (kh * 32 + c0) ^ xorm;
#pragma unroll
      for (int dt = 0; dt < 8; ++dt) {
        short8 b = *(const short8*)&vs[(dt * 16 + (lane & 15)) * 64 + col];
        of[dt] = __builtin_amdgcn_mfma_f32_16x16x32_bf16(a, b, of[dt], 0, 0, 0);
      }
    }
    __builtin_amdgcn_s_setprio(0);
    // own prefetch landed; single barrier per tile
    asm volatile("s_waitcnt vmcnt(0)" ::: "memory");
    __builtin_amdgcn_s_barrier();
    cur ^= 1;
  }
#pragma unroll
  for (int r = 0; r < 4; ++r) lsum[r] = 1.f / lsum[r];
  u16* op = O + (size_t)(qrow + ((lane >> 4) << 2)) * 4096 + h * 128 + (lane & 15);
#pragma unroll
  for (int dt = 0; dt < 8; ++dt)
#pragma unroll
    for (int r = 0; r < 4; ++r)
      op[(size_t)r * 4096 + dt * 16] = f2bf(of[dt][r] * lsum[r]);
}

extern "C" void kernel_launch(void* const* d_in, const int* in_sizes, int n_in,
                              void* d_out, int out_size, void* d_ws, size_t ws_size,
                              hipStream_t stream) {
  (void)in_sizes; (void)n_in; (void)out_size;
  const float* hs = (const float*)d_in[0];
  const float* Wq = (const float*)d_in[3];
  const float* Wk = (const float*)d_in[4];
  const float* Wv = (const float*)d_in[5];
  const float* Wo = (const float*)d_in[6];
  float* out = (float*)d_out;
  char* ws = (char*)d_ws;

  u16* Xb   = (u16*)(ws + 0);          // 16 MB : X bf16 [2048][4096]
  u16* Wt   = (u16*)(ws + 16777216);   // 32 MB : Wq^T then Wo^T [4096][4096]
  u16* WkvT = (u16*)(ws + 50331648);   // 16 MB : [Wk^T;Wv^T] [2048][4096]
  u16* Qb   = (u16*)(ws + 67108864);   // 16 MB : Q [2048][4096]
  u16* KVb  = (u16*)(ws + 83886080);   // 8 MB  : K|V [2048][2048]
  u16* Vtb  = (u16*)(ws + 92274688);   // 4 MB  : V^T [1024][2048]
  u16* Ab   = (u16*)(ws + 96468992);   // 16 MB : attn out [2048][4096]
  if (ws_size < 113246208u) return;

  cvt_f32_bf16_kernel<<<dim3(2097152 / 256), 256, 0, stream>>>(hs, Xb, 2097152);

  // Q projection
  tconv_f32_kernel<<<dim3(128, 128), dim3(32, 8), 0, stream>>>(Wq, Wt, 4096, 4096);
  gemm_bt_kernel<0><<<dim3(32, 16), 256, 0, stream>>>(Xb, Wt, Qb, 2048, 4096, 4096);

  // fused K+V projection
  tconv_f32_kernel<<<dim3(32, 128), dim3(32, 8), 0, stream>>>(Wk, WkvT, 4096, 1024);
  tconv_f32_kernel<<<dim3(32, 128), dim3(32, 8), 0, stream>>>(Wv, WkvT + (size_t)1024 * 4096, 4096, 1024);
  gemm_bt_kernel<0><<<dim3(16, 16), 256, 0, stream>>>(Xb, WkvT, KVb, 2048, 2048, 4096);

  // RoPE; Q gets log2(e)/sqrt(128) folded in for exp2-domain softmax
  rope_kernel<<<dim3(16384), 256, 0, stream>>>(Qb, 4096, 31, 5, 2048 * 32 * 64, 0.12751781828987514f);
  rope_kernel<<<dim3(4096), 256, 0, stream>>>(KVb, 2048, 7, 3, 2048 * 8 * 64, 1.0f);

  // V^T for attention PV
  t_bf16_kernel<<<dim3(32, 64), dim3(32, 8), 0, stream>>>(KVb + 1024, Vtb, 2048, 2048, 1024);

  attn_kernel<<<dim3(32, 32), 256, 0, stream>>>(Qb, KVb, Vtb, Ab);

  // output projection
  tconv_f32_kernel<<<dim3(128, 128), dim3(32, 8), 0, stream>>>(Wo, Wt, 4096, 4096);
  gemm_bt_kernel<1><<<dim3(32, 16), 256, 0, stream>>>(Ab, Wt, out, 2048, 4096, 4096);
}

// Round 4
// 389.486 us; speedup vs baseline: 1.0490x; 1.0490x over previous
//
#include <hip/hip_runtime.h>

typedef __attribute__((ext_vector_type(8))) short short8;
typedef __attribute__((ext_vector_type(4))) short s16x4;
typedef __attribute__((ext_vector_type(4))) float f32x4;
typedef unsigned short u16;
typedef unsigned int u32;

__device__ __forceinline__ u16 f2bf(float f) {
  union { float f; unsigned int u; } v; v.f = f;
  unsigned int r = (v.u + 0x7FFFu + ((v.u >> 16) & 1u)) >> 16;
  return (u16)r;
}
__device__ __forceinline__ float bf2f(u16 b) {
  union { unsigned int u; float f; } v; v.u = ((unsigned int)b) << 16;
  return v.f;
}
__device__ __forceinline__ void load_lds16(const void* g, void* l) {
  __builtin_amdgcn_global_load_lds((const __attribute__((address_space(1))) void*)g,
                                   (__attribute__((address_space(3))) void*)l, 16, 0, 0);
}

// ---------------- fp32 -> bf16 elementwise ----------------
__global__ void cvt_f32_bf16_kernel(const float* __restrict__ in, u16* __restrict__ out, int n4) {
  int i = blockIdx.x * blockDim.x + threadIdx.x;
  if (i >= n4) return;
  float4 v = ((const float4*)in)[i];
  ushort4 o;
  o.x = f2bf(v.x); o.y = f2bf(v.y); o.z = f2bf(v.z); o.w = f2bf(v.w);
  ((ushort4*)out)[i] = o;
}

// ---------------- fp32 [K][N] -> bf16 [N][K] transpose ----------------
__global__ void tconv_f32_kernel(const float* __restrict__ W, u16* __restrict__ Wt, int K, int N) {
  __shared__ float tile[32][33];
  int tx = threadIdx.x, ty = threadIdx.y;
  int nb = blockIdx.x * 32, kb = blockIdx.y * 32;
#pragma unroll
  for (int i = ty; i < 32; i += 8)
    tile[i][tx] = W[(size_t)(kb + i) * N + nb + tx];
  __syncthreads();
#pragma unroll
  for (int i = ty; i < 32; i += 8)
    Wt[(size_t)(nb + i) * K + kb + tx] = f2bf(tile[tx][i]);
}

// ---------------- bf16 [R][C-slice] -> bf16 [C][R] transpose ----------------
__global__ void t_bf16_kernel(const u16* __restrict__ V, u16* __restrict__ Vt, int ldv, int R, int C) {
  __shared__ u16 tile[32][33];
  int tx = threadIdx.x, ty = threadIdx.y;
  int cb = blockIdx.x * 32, rb = blockIdx.y * 32;
#pragma unroll
  for (int i = ty; i < 32; i += 8)
    tile[i][tx] = V[(size_t)(rb + i) * ldv + cb + tx];
  __syncthreads();
#pragma unroll
  for (int i = ty; i < 32; i += 8)
    Vt[(size_t)(cb + i) * R + rb + tx] = tile[tx][i];
}

// ---------------- RoPE in-place on bf16 [S][*], head cols at hh*128 ----------------
__global__ void rope_kernel(u16* __restrict__ X, int ld, int hmask, int hshift, int total, float scale) {
  int idx = blockIdx.x * blockDim.x + threadIdx.x;
  if (idx >= total) return;
  int j = idx & 63;
  int t = idx >> 6;
  int hh = t & hmask;
  int s = t >> hshift;
  float invf = exp2f(-(float)j * (13.287712379549449f / 64.0f)); // 10000^(-j/64)
  float ang = (float)s * invf;
  float sn, cs;
  sincosf(ang, &sn, &cs);
  u16* p = X + (size_t)s * ld + hh * 128 + j;
  float a = bf2f(p[0]), b = bf2f(p[64]);
  p[0]  = f2bf((a * cs - b * sn) * scale);
  p[64] = f2bf((b * cs + a * sn) * scale);
}

// ---------------- bf16 GEMM: C[M][N] = A[M][K] * Bt[N][K]^T ----------------
template<int OUTF32>
__global__ __launch_bounds__(256, 2) void gemm_bt_kernel(
    const u16* __restrict__ A, const u16* __restrict__ B,
    void* __restrict__ C, int M, int N, int K) {
  __shared__ u16 As[128 * 64];
  __shared__ u16 Bs[128 * 64];
  int tid = threadIdx.x, lane = tid & 63, w = tid >> 6;
  int wr = w >> 1, wc = w & 1;
  int nbx = gridDim.x;
  int flat = blockIdx.y * nbx + blockIdx.x;
  int cpx = (nbx * gridDim.y) >> 3;
  flat = (flat & 7) * cpx + (flat >> 3);
  int m0 = (flat / nbx) * 128, n0 = (flat % nbx) * 128;
  f32x4 acc[4][4];
#pragma unroll
  for (int i = 0; i < 4; ++i)
#pragma unroll
    for (int j = 0; j < 4; ++j) acc[i][j] = (f32x4){0.f, 0.f, 0.f, 0.f};
  int srow = tid >> 3;
  int scol = ((tid & 7) ^ (srow & 7)) << 3;
  const u16* ga = A + (size_t)(m0 + srow) * K + scol;
  const u16* gb = B + (size_t)(n0 + srow) * K + scol;
  int xorm = (lane & 7) << 3;
  int arow = wr * 64 + (lane & 15);
  int brow = wc * 64 + (lane & 15);
  int c0 = (lane >> 4) << 3;
  int nkt = K >> 6;
  for (int kt = 0; kt < nkt; ++kt) {
#pragma unroll
    for (int it = 0; it < 4; ++it) {
      load_lds16(ga + (size_t)it * 32 * K + kt * 64, (char*)As + (it * 256 + w * 64) * 16);
      load_lds16(gb + (size_t)it * 32 * K + kt * 64, (char*)Bs + (it * 256 + w * 64) * 16);
    }
    __syncthreads();
#pragma unroll
    for (int kk = 0; kk < 2; ++kk) {
      int col = (kk * 32 + c0) ^ xorm;
      short8 af[4], bfr[4];
#pragma unroll
      for (int m = 0; m < 4; ++m) af[m]  = *(const short8*)&As[(arow + m * 16) * 64 + col];
#pragma unroll
      for (int n = 0; n < 4; ++n) bfr[n] = *(const short8*)&Bs[(brow + n * 16) * 64 + col];
#pragma unroll
      for (int m = 0; m < 4; ++m)
#pragma unroll
        for (int n = 0; n < 4; ++n)
          acc[m][n] = __builtin_amdgcn_mfma_f32_16x16x32_bf16(af[m], bfr[n], acc[m][n], 0, 0, 0);
    }
    __syncthreads();
  }
  int crow = m0 + wr * 64 + ((lane >> 4) << 2);
  int ccol = n0 + wc * 64 + (lane & 15);
#pragma unroll
  for (int m = 0; m < 4; ++m)
#pragma unroll
    for (int n = 0; n < 4; ++n)
#pragma unroll
      for (int r = 0; r < 4; ++r) {
        size_t off = (size_t)(crow + m * 16 + r) * N + ccol + n * 16;
        if (OUTF32) ((float*)C)[off] = acc[m][n][r];
        else        ((u16*)C)[off]   = f2bf(acc[m][n][r]);
      }
}

// ---------------- flash attention, sliding window 1024, GQA 32/8 ----------------
// grid (S/64, H). block 256 = 4 waves; wave w owns q rows [q0+16w, +16).
// SWAPPED QK^T: sf = mfma(K_frag, Q_frag) -> S^T fragment, each lane owns 16
// scores of ONE q-row (q = lane&15, k = nt*16 + (lane>>4)*4 + r). Softmax is
// in-register (15 VALU + 2 shfl) instead of 40 chained shfls. P re-fragmented
// for PV via v_perm pack + 16 independent shfls (no LDS round-trip).
// K double-buffered, V single-buffered. LDS 48KB -> 3 blocks/CU.
__global__ __launch_bounds__(256, 3) void attn_kernel(
    const u16* __restrict__ Q, const u16* __restrict__ Kg,
    const u16* __restrict__ Vt, u16* __restrict__ O) {
  __shared__ u16 Ks[2][64 * 128];
  __shared__ u16 Vs[128 * 64];
  int tid = threadIdx.x, lane = tid & 63, w = tid >> 6;
  int g = lane >> 4, q = lane & 15;
  int q0 = blockIdx.x * 64;
  int h = blockIdx.y, hk = h >> 2;
  int qrow = q0 + w * 16;
  int xorm = (lane & 7) << 3;
  // Q fragment (B-operand): lane holds Q[qrow+q][g*8 + i + 32*kk]
  short8 qf[4];
  {
    const u16* qp = Q + (size_t)(qrow + q) * 4096 + h * 128 + g * 8;
#pragma unroll
    for (int kk = 0; kk < 4; ++kk) qf[kk] = *(const short8*)(qp + kk * 32);
  }
  float mrow = -1e30f, lsum = 0.f;
  f32x4 of[8];
#pragma unroll
  for (int d = 0; d < 8; ++d) of[d] = (f32x4){0.f, 0.f, 0.f, 0.f};
  int jt_lo = (q0 >= 1024) ? ((q0 - 1023) >> 6) : 0;
  int jt_hi = q0 >> 6;
  int krow = tid >> 4;
  int kchunk = (tid & 15) ^ (krow & 7);
  const u16* kbase = Kg + (size_t)krow * 2048 + hk * 128 + (kchunk << 3);
  int vrow = tid >> 3;
  int vchunk = (tid & 7) ^ (vrow & 7);
  const u16* vbase = Vt + (size_t)(hk * 128 + vrow) * 2048 + (vchunk << 3);

  auto stageK = [&](int buf, int j0) {
    const u16* gp = kbase + (size_t)j0 * 2048;
#pragma unroll
    for (int it = 0; it < 4; ++it)
      load_lds16(gp + (size_t)it * 16 * 2048, (char*)(&Ks[buf][0]) + (it * 256 + w * 64) * 16);
  };
  auto stageV = [&](int j0) {
    const u16* gp = vbase + j0;
#pragma unroll
    for (int it = 0; it < 4; ++it)
      load_lds16(gp + (size_t)it * 32 * 2048, (char*)Vs + (it * 256 + w * 64) * 16);
  };

  int cur = 0;
  stageK(0, jt_lo << 6);
  asm volatile("s_waitcnt vmcnt(0)" ::: "memory");
  __syncthreads();
  for (int jt = jt_lo; jt <= jt_hi; ++jt) {
    int j0 = jt << 6;
    stageV(j0);                                  // 4 loads (current V)
    if (jt < jt_hi) stageK(cur ^ 1, j0 + 64);    // 4 loads (next K, stays in flight)
    // S^T = K Q^T
    f32x4 sf[4];
#pragma unroll
    for (int nt = 0; nt < 4; ++nt) sf[nt] = (f32x4){0.f, 0.f, 0.f, 0.f};
    const u16* ks = &Ks[cur][0];
    __builtin_amdgcn_s_setprio(1);
#pragma unroll
    for (int kk = 0; kk < 4; ++kk) {
      short8 qv = qf[kk];
      int col = (kk * 32 + g * 8) ^ xorm;
#pragma unroll
      for (int nt = 0; nt < 4; ++nt) {
        short8 kf = *(const short8*)&ks[(nt * 16 + q) * 128 + col];
        sf[nt] = __builtin_amdgcn_mfma_f32_16x16x32_bf16(kf, qv, sf[nt], 0, 0, 0);
      }
    }
    __builtin_amdgcn_s_setprio(0);
    // mask (boundary tiles only; per lane: row q = qrow+q, keys in regs)
    float p[4][4];
#pragma unroll
    for (int nt = 0; nt < 4; ++nt)
#pragma unroll
      for (int r = 0; r < 4; ++r) p[nt][r] = sf[nt][r];
    if (j0 + 63 > qrow || j0 + 1009 <= qrow) {
      int qq = qrow + q;
      int kb = j0 + g * 4;
#pragma unroll
      for (int nt = 0; nt < 4; ++nt)
#pragma unroll
        for (int r = 0; r < 4; ++r) {
          int key = kb + nt * 16 + r;
          if (key > qq || key + 1024 <= qq) p[nt][r] = -1e9f;
        }
    }
    // online softmax, exp2-domain, in-register row reduce
    float tm = p[0][0];
#pragma unroll
    for (int nt = 0; nt < 4; ++nt)
#pragma unroll
      for (int r = 0; r < 4; ++r) tm = fmaxf(tm, p[nt][r]);
    tm = fmaxf(tm, __shfl_xor(tm, 16));
    tm = fmaxf(tm, __shfl_xor(tm, 32));
    if (__any(tm > mrow + 8.f)) {
      float nm = fmaxf(mrow, tm);
      float sc = __builtin_amdgcn_exp2f(mrow - nm);
      mrow = nm;
      lsum *= sc;
#pragma unroll
      for (int d = 0; d < 8; ++d) of[d] *= sc;
    }
    float ps = 0.f;
#pragma unroll
    for (int nt = 0; nt < 4; ++nt)
#pragma unroll
      for (int r = 0; r < 4; ++r) {
        float e = __builtin_amdgcn_exp2f(p[nt][r] - mrow);
        p[nt][r] = e;
        ps += e;
      }
    ps += __shfl_xor(ps, 16);
    ps += __shfl_xor(ps, 32);
    lsum += ps;
    // pack P (truncating bf16 pairs) : pk[nt] = {(r0,r1),(r2,r3)}
    u32 pk[4][2];
#pragma unroll
    for (int nt = 0; nt < 4; ++nt) {
      pk[nt][0] = __builtin_amdgcn_perm(__float_as_uint(p[nt][1]), __float_as_uint(p[nt][0]), 0x07060302u);
      pk[nt][1] = __builtin_amdgcn_perm(__float_as_uint(p[nt][3]), __float_as_uint(p[nt][2]), 0x07060302u);
    }
    // V (own 4 oldest loads) visible to all waves after barrier
    if (jt < jt_hi) { asm volatile("s_waitcnt vmcnt(4)" ::: "memory"); }
    else            { asm volatile("s_waitcnt vmcnt(0)" ::: "memory"); }
    __builtin_amdgcn_s_barrier();
    // O^T += V^T P^T : re-fragment P via shfl exchange, then 2x8 MFMA
    int s0 = q + ((g & 1) ? 32 : 0);
    int s1 = s0 + 16;
    bool hi_sel = g >= 2;
    __builtin_amdgcn_s_setprio(1);
#pragma unroll
    for (int kh = 0; kh < 2; ++kh) {
      int lo = kh * 2, hi = lo + 1;
      u32 a0 = (u32)__shfl((int)pk[lo][0], s0);
      u32 a1 = (u32)__shfl((int)pk[lo][1], s0);
      u32 b0 = (u32)__shfl((int)pk[hi][0], s0);
      u32 b1 = (u32)__shfl((int)pk[hi][1], s0);
      u32 a2 = (u32)__shfl((int)pk[lo][0], s1);
      u32 a3 = (u32)__shfl((int)pk[lo][1], s1);
      u32 b2 = (u32)__shfl((int)pk[hi][0], s1);
      u32 b3 = (u32)__shfl((int)pk[hi][1], s1);
      union { u32 u[4]; short8 s; } pb;
      pb.u[0] = hi_sel ? b0 : a0;
      pb.u[1] = hi_sel ? b1 : a1;
      pb.u[2] = hi_sel ? b2 : a2;
      pb.u[3] = hi_sel ? b3 : a3;
      int col = (kh * 32 + g * 8) ^ xorm;
#pragma unroll
      for (int dt = 0; dt < 8; ++dt) {
        short8 vv = *(const short8*)&Vs[(dt * 16 + q) * 64 + col];
        of[dt] = __builtin_amdgcn_mfma_f32_16x16x32_bf16(vv, pb.s, of[dt], 0, 0, 0);
      }
    }
    __builtin_amdgcn_s_setprio(0);
    // drain K prefetch; Vs free for next iter's stage
    asm volatile("s_waitcnt vmcnt(0)" ::: "memory");
    __builtin_amdgcn_s_barrier();
    cur ^= 1;
  }
  float inv = 1.f / lsum;
  // O^T fragment: lane holds O[qrow+q][dt*16 + g*4 + r]
  u16* op = O + (size_t)(qrow + q) * 4096 + h * 128 + g * 4;
#pragma unroll
  for (int dt = 0; dt < 8; ++dt) {
    s16x4 o4;
#pragma unroll
    for (int r = 0; r < 4; ++r) o4[r] = (short)f2bf(of[dt][r] * inv);
    *(s16x4*)(op + dt * 16) = o4;
  }
}

extern "C" void kernel_launch(void* const* d_in, const int* in_sizes, int n_in,
                              void* d_out, int out_size, void* d_ws, size_t ws_size,
                              hipStream_t stream) {
  (void)in_sizes; (void)n_in; (void)out_size;
  const float* hs = (const float*)d_in[0];
  const float* Wq = (const float*)d_in[3];
  const float* Wk = (const float*)d_in[4];
  const float* Wv = (const float*)d_in[5];
  const float* Wo = (const float*)d_in[6];
  float* out = (float*)d_out;
  char* ws = (char*)d_ws;

  u16* Xb   = (u16*)(ws + 0);          // 16 MB : X bf16 [2048][4096]
  u16* Wt   = (u16*)(ws + 16777216);   // 32 MB : Wq^T then Wo^T [4096][4096]
  u16* WkvT = (u16*)(ws + 50331648);   // 16 MB : [Wk^T;Wv^T] [2048][4096]
  u16* Qb   = (u16*)(ws + 67108864);   // 16 MB : Q [2048][4096]
  u16* KVb  = (u16*)(ws + 83886080);   // 8 MB  : K|V [2048][2048]
  u16* Vtb  = (u16*)(ws + 92274688);   // 4 MB  : V^T [1024][2048]
  u16* Ab   = (u16*)(ws + 96468992);   // 16 MB : attn out [2048][4096]
  if (ws_size < 113246208u) return;

  cvt_f32_bf16_kernel<<<dim3(2097152 / 256), 256, 0, stream>>>(hs, Xb, 2097152);

  // Q projection
  tconv_f32_kernel<<<dim3(128, 128), dim3(32, 8), 0, stream>>>(Wq, Wt, 4096, 4096);
  gemm_bt_kernel<0><<<dim3(32, 16), 256, 0, stream>>>(Xb, Wt, Qb, 2048, 4096, 4096);

  // fused K+V projection
  tconv_f32_kernel<<<dim3(32, 128), dim3(32, 8), 0, stream>>>(Wk, WkvT, 4096, 1024);
  tconv_f32_kernel<<<dim3(32, 128), dim3(32, 8), 0, stream>>>(Wv, WkvT + (size_t)1024 * 4096, 4096, 1024);
  gemm_bt_kernel<0><<<dim3(16, 16), 256, 0, stream>>>(Xb, WkvT, KVb, 2048, 2048, 4096);

  // RoPE; Q gets log2(e)/sqrt(128) folded in for exp2-domain softmax
  rope_kernel<<<dim3(16384), 256, 0, stream>>>(Qb, 4096, 31, 5, 2048 * 32 * 64, 0.12751781828987514f);
  rope_kernel<<<dim3(4096), 256, 0, stream>>>(KVb, 2048, 7, 3, 2048 * 8 * 64, 1.0f);

  // V^T for attention PV
  t_bf16_kernel<<<dim3(32, 64), dim3(32, 8), 0, stream>>>(KVb + 1024, Vtb, 2048, 2048, 1024);

  attn_kernel<<<dim3(32, 32), 256, 0, stream>>>(Qb, KVb, Vtb, Ab);

  // output projection
  tconv_f32_kernel<<<dim3(128, 128), dim3(32, 8), 0, stream>>>(Wo, Wt, 4096, 4096);
  gemm_bt_kernel<1><<<dim3(32, 16), 256, 0, stream>>>(Ab, Wt, out, 2048, 4096, 4096);
}